// Round 15
// baseline (60.416 us; speedup 1.0000x reference)
//
#include <hip/hip_runtime.h>

typedef unsigned short u16;
typedef __attribute__((ext_vector_type(4))) float f32x4;
typedef __attribute__((ext_vector_type(8))) short bf16x8;
typedef __attribute__((ext_vector_type(4))) u16 u16x4;
typedef __attribute__((ext_vector_type(8))) u16 u16x8;

#define MFMA(a, b, c) __builtin_amdgcn_mfma_f32_16x16x32_bf16(a, b, c, 0, 0, 0)

__device__ __forceinline__ u16 f2bf(float f) {
    unsigned u = __float_as_uint(f);
    u += 0x7fffu + ((u >> 16) & 1u);   // round-to-nearest-even
    return (u16)(u >> 16);
}
__device__ __forceinline__ float bf2f(u16 h) {
    unsigned u = ((unsigned)h) << 16;
    return __uint_as_float(u);
}

__device__ __forceinline__ void load_lds16(const void* g, void* l) {
    __builtin_amdgcn_global_load_lds((const __attribute__((address_space(1))) void*)g,
                                     (__attribute__((address_space(3))) void*)l,
                                     16, 0, 0);
}

// ---------------------------------------------------------------------------
// Kernel 1: pack Wq|Wk|Wv (fp32 [1024][64]) -> Wtt bf16, per-matrix tile-major
// + swizzled: Wtt[(mat*16+kt)*64 + n][ ((c^(n&7))<<3)+ci ]  (8KB per (mat,kt)
// tile, staged linearly; swizzle baked into global layout).
// ---------------------------------------------------------------------------
__global__ void wt_pack(const float* __restrict__ Wq, const float* __restrict__ Wk,
                        const float* __restrict__ Wv, u16* __restrict__ Wtt) {
    const int k = blockIdx.x;        // 0..1023
    const int n = threadIdx.x;       // 0..191
    const float* W = (n < 64) ? Wq : (n < 128 ? Wk : Wv);
    const float v = W[(size_t)k * 64 + (n & 63)];
    const int mat = n >> 6, nl = n & 63;
    const int kt = k >> 6, ks = k & 63, c = ks >> 3, ci = ks & 7;
    Wtt[(size_t)((mat * 16 + kt) * 64 + nl) * 64 + (((c ^ (nl & 7)) << 3) + ci)] = f2bf(v);
}

// ---------------------------------------------------------------------------
// Kernel 2: qkv projection as 3 independent GEMMs (mat = blockIdx>>8).
// BM=64, N=64, BK=64, 4 waves (wave owns one 16-col n-frag, all 4 m-frags).
// LDS 48KB (xs 2x16KB + ws 2x8KB) -> 3 blocks/CU, grid 768 = fully
// co-resident; blocks mt, mt+256, mt+512 share x-tiles on the SAME XCD.
// m97 2-phase global_load_lds staging; 64-wide swizzles (conflict-free).
// Q pre-scaled by log2(e)/sqrt(1024).
// ---------------------------------------------------------------------------
__global__ __launch_bounds__(256, 3) void qkv_gemm(const float* __restrict__ x,
                                                   const u16* __restrict__ Wtt,
                                                   u16* __restrict__ qo,
                                                   u16* __restrict__ ko,
                                                   u16* __restrict__ vT) {
    const int tid = threadIdx.x;
    const int lane = tid & 63, wave = tid >> 6;
    const int lr = lane & 15, lg = lane >> 4;
    const int mat = blockIdx.x >> 8;          // 0=q, 1=k, 2=v
    const int m0 = (blockIdx.x & 255) * 64;

    __shared__ __align__(16) float xs[2][64 * 64];   // 16KB each
    __shared__ __align__(16) u16 ws[2][64 * 64];     // 8KB each

    f32x4 acc[4];
#pragma unroll
    for (int m = 0; m < 4; ++m) acc[m] = (f32x4){0.f, 0.f, 0.f, 0.f};

#define QSTAGE(bufi, kt_)                                                               \
    {                                                                                   \
        _Pragma("unroll") for (int j = 0; j < 4; ++j) {                                 \
            const int cid = j * 256 + tid;                                              \
            const int row = cid >> 4, cc = cid & 15;                                    \
            load_lds16(x + (size_t)(m0 + row) * 1024 + (kt_)*64 +                       \
                           ((cc ^ (row & 7)) << 2),                                     \
                       &xs[bufi][(j * 256 + wave * 64) * 4]);                           \
        }                                                                               \
        _Pragma("unroll") for (int j = 0; j < 2; ++j) {                                 \
            const int cid = j * 256 + tid;                                              \
            load_lds16(Wtt + (size_t)(mat * 16 + (kt_)) * 4096 + cid * 8,               \
                       &ws[bufi][(j * 256 + wave * 64) * 8]);                           \
        }                                                                               \
    }

    QSTAGE(0, 0);
    __syncthreads();

    for (int kt = 0; kt < 16; ++kt) {
        const int cur = kt & 1;
        if (kt < 15) QSTAGE(cur ^ 1, kt + 1);

#pragma unroll
        for (int h = 0; h < 2; ++h) {
            const int wrow = wave * 16 + lr;
            const int cb = h * 4 + lg;
            const bf16x8 b = *(const bf16x8*)&ws[cur][wrow * 64 + ((cb ^ (wrow & 7)) << 3)];
#pragma unroll
            for (int mm = 0; mm < 4; ++mm) {
                const int rr = mm * 16 + lr;
                const int c0 = h * 8 + lg * 2;
                f32x4 f0 = *(const f32x4*)&xs[cur][rr * 64 + ((c0 ^ (rr & 7)) << 2)];
                f32x4 f1 = *(const f32x4*)&xs[cur][rr * 64 + (((c0 + 1) ^ (rr & 7)) << 2)];
                bf16x8 a;
#pragma unroll
                for (int i = 0; i < 4; ++i) {
                    a[i] = (short)f2bf(f0[i]);
                    a[i + 4] = (short)f2bf(f1[i]);
                }
                acc[mm] = MFMA(a, b, acc[mm]);
            }
        }
        __syncthreads();
    }

    const float SCQ = 0.0450842200277801f;   // log2(e)/sqrt(1024)
    const int col = wave * 16 + lr;
    if (mat == 0) {
#pragma unroll
        for (int mm = 0; mm < 4; ++mm) {
            const int rl = m0 + mm * 16 + lg * 4;
#pragma unroll
            for (int r = 0; r < 4; ++r)
                qo[(size_t)(rl + r) * 64 + col] = f2bf(acc[mm][r] * SCQ);
        }
    } else if (mat == 1) {
#pragma unroll
        for (int mm = 0; mm < 4; ++mm) {
            const int rl = m0 + mm * 16 + lg * 4;
#pragma unroll
            for (int r = 0; r < 4; ++r)
                ko[(size_t)(rl + r) * 64 + col] = f2bf(acc[mm][r]);
        }
    } else {
        const int bb = m0 >> 11;
        const int tb = m0 & 2047;
#pragma unroll
        for (int mm = 0; mm < 4; ++mm) {
            u16x4 pk;
#pragma unroll
            for (int r = 0; r < 4; ++r) pk[r] = f2bf(acc[mm][r]);
            *(u16x4*)&vT[(size_t)(bb * 64 + col) * 2048 + tb + mm * 16 + lg * 4] = pk;
        }
    }
}

// ---------------------------------------------------------------------------
// Kernel 3: causal attention — R13 structure + s_setprio (kept: ~+2us).
// 2-phase global_load_lds dbuf, 640 blocks, 64 q-rows/block, 3 blocks/CU,
// fixed-max softmax, bf16 partials.
// ---------------------------------------------------------------------------
#define PPITCH 72
__global__ __launch_bounds__(256, 3) void attn_part(const u16* __restrict__ q,
                                                    const u16* __restrict__ k,
                                                    const u16* __restrict__ vT,
                                                    u16* __restrict__ Opb,
                                                    float* __restrict__ Lp) {
    const int b = blockIdx.x & 7;
    int g = blockIdx.x >> 3;                  // 0..79, heavy-first
    int qt = 31, rem = g;
    while (rem >= (qt >> 3) + 1) { rem -= (qt >> 3) + 1; --qt; }
    const int c0 = rem;
    const int q0 = qt * 64;
    const int kv_lo = c0 * 512;
    const int kv_hi = min(kv_lo + 512, q0 + 64);
    const int ntiles = (kv_hi - kv_lo) >> 6;
    const int slot = (b * 32 + qt) * 4 + c0;

    __shared__ __align__(16) u16 lK[2][64 * 64];     // 8KB each
    __shared__ __align__(16) u16 lV[2][64 * 64];     // 8KB each
    __shared__ __align__(16) u16 lP[4][16 * PPITCH]; // per-wave P

    const int tid = threadIdx.x;
    const int wave = tid >> 6, lane = tid & 63;
    const int lr = lane & 15, lg = lane >> 4;

    const u16* qb = q + (size_t)b * 2048 * 64;
    const u16* kb = k + (size_t)b * 2048 * 64;
    const u16* vb = vT + (size_t)b * 64 * 2048;

    const int myrow = q0 + wave * 16 + lr;
    const bf16x8 qf0 = *(const bf16x8*)(qb + (size_t)myrow * 64 + lg * 8);
    const bf16x8 qf1 = *(const bf16x8*)(qb + (size_t)myrow * 64 + 32 + lg * 8);

    f32x4 oacc[4];
#pragma unroll
    for (int n = 0; n < 4; ++n) oacc[n] = (f32x4){0.f, 0.f, 0.f, 0.f};
    float rs = 0.f;

#define ASTAGE(bufi, kv0_)                                                             \
    {                                                                                  \
        _Pragma("unroll") for (int j = 0; j < 2; ++j) {                                \
            const int cid = j * 256 + wave * 64 + lane;                                \
            const int row = cid >> 3, cc = cid & 7;                                    \
            load_lds16(kb + (size_t)((kv0_) + row) * 64 + ((cc ^ (row & 7)) << 3),     \
                       &lK[bufi][(j * 256 + wave * 64) * 8]);                          \
            load_lds16(vb + (size_t)row * 2048 + (kv0_) + ((cc ^ (row & 7)) << 3),     \
                       &lV[bufi][(j * 256 + wave * 64) * 8]);                          \
        }                                                                              \
    }

    ASTAGE(0, kv_lo);
    __syncthreads();

    for (int it = 0; it < ntiles; ++it) {
        const int cur = it & 1;
        if (it + 1 < ntiles) ASTAGE(cur ^ 1, kv_lo + (it + 1) * 64);

        const int kv0 = kv_lo + it * 64;
        if (kv0 <= q0 + wave * 16 + 15) {      // wave-uniform causal guard
            f32x4 s[4];
            __builtin_amdgcn_s_setprio(1);
#pragma unroll
            for (int n = 0; n < 4; ++n) {
                const int row = n * 16 + lr;
                const bf16x8 kf0 = *(const bf16x8*)&lK[cur][row * 64 + ((lg ^ (row & 7)) << 3)];
                const bf16x8 kf1 =
                    *(const bf16x8*)&lK[cur][row * 64 + (((4 + lg) ^ (row & 7)) << 3)];
                f32x4 a = (f32x4){0.f, 0.f, 0.f, 0.f};
                a = MFMA(kf0, qf0, a);
                a = MFMA(kf1, qf1, a);
                s[n] = a;   // S^T: rows kv = 16n+lg*4+r, col q = lr
            }
            __builtin_amdgcn_s_setprio(0);

            const bool msk = (kv0 + 63 > q0 + wave * 16);
#pragma unroll
            for (int n = 0; n < 4; ++n) {
                u16x4 pk;
#pragma unroll
                for (int r = 0; r < 4; ++r) {
                    const int kvi = kv0 + n * 16 + lg * 4 + r;
                    const float p = (!msk || kvi <= myrow) ? exp2f(s[n][r]) : 0.f;
                    rs += p;
                    pk[r] = f2bf(p);
                }
                *(u16x4*)&lP[wave][lr * PPITCH + n * 16 + lg * 4] = pk;
            }

            __builtin_amdgcn_s_setprio(1);
#pragma unroll
            for (int kc = 0; kc < 2; ++kc) {
                const bf16x8 pf = *(const bf16x8*)&lP[wave][lr * PPITCH + kc * 32 + lg * 8];
#pragma unroll
                for (int n = 0; n < 4; ++n) {
                    const int row = n * 16 + lr;
                    const bf16x8 vf =
                        *(const bf16x8*)&lV[cur][row * 64 + (((kc * 4 + lg) ^ (row & 7)) << 3)];
                    oacc[n] = MFMA(pf, vf, oacc[n]);
                }
            }
            __builtin_amdgcn_s_setprio(0);
        }
        __syncthreads();
    }

    // ---- row-sum across the 4 lanes sharing lr
    rs += __shfl_xor(rs, 16);
    rs += __shfl_xor(rs, 32);
    if (lane < 16) Lp[slot * 64 + wave * 16 + lr] = rs;

    // ---- bf16 partials, MFMA-native layout
    u16* op = Opb + (size_t)slot * 4096 + wave * 1024;
#pragma unroll
    for (int n = 0; n < 4; ++n)
#pragma unroll
        for (int r = 0; r < 4; ++r)
            op[n * 256 + (lg * 4 + r) * 16 + lr] = f2bf(oacc[n][r]);
}

// ---------------------------------------------------------------------------
// Kernel 4: vectorized merge (unchanged from R13).
// ---------------------------------------------------------------------------
__global__ __launch_bounds__(256) void attn_combine(const u16* __restrict__ Opb,
                                                    const float* __restrict__ Lp,
                                                    float* __restrict__ out) {
    const int gid = blockIdx.x * 256 + threadIdx.x;   // 131072
    const int colg = gid & 7;
    const int row = gid >> 3;            // b*2048 + t
    const int b = row >> 11, tt = row & 2047;
    const int qt = tt >> 6, i = tt & 63;
    const int nc = (qt >> 3) + 1;
    const size_t sbase = (size_t)(b * 32 + qt) * 4;
    const int sub0 = (i >> 4) * 1024 + (colg >> 1) * 256 + (i & 15) * 16 + (colg & 1) * 8;

    float O[8] = {0.f, 0.f, 0.f, 0.f, 0.f, 0.f, 0.f, 0.f};
    float L = 0.f;
    for (int c = 0; c < nc; ++c) {
        const u16x8 v = *(const u16x8*)&Opb[(sbase + c) * 4096 + sub0];
#pragma unroll
        for (int j = 0; j < 8; ++j) O[j] += bf2f(v[j]);
        L += Lp[(sbase + c) * 64 + i];
    }
    const float rinv = 1.0f / L;
    f32x4 o0, o1;
#pragma unroll
    for (int j = 0; j < 4; ++j) {
        o0[j] = O[j] * rinv;
        o1[j] = O[4 + j] * rinv;
    }
    float* ob = out + (size_t)row * 64 + colg * 8;
    *(f32x4*)(ob) = o0;
    *(f32x4*)(ob + 4) = o1;
}

// ---------------------------------------------------------------------------
extern "C" void kernel_launch(void* const* d_in, const int* in_sizes, int n_in,
                              void* d_out, int out_size, void* d_ws, size_t ws_size,
                              hipStream_t stream) {
    const float* x = (const float*)d_in[0];
    const float* Wq = (const float*)d_in[1];
    const float* Wk = (const float*)d_in[2];
    const float* Wv = (const float*)d_in[3];
    float* out = (float*)d_out;

    char* ws = (char*)d_ws;
    u16* Wtt = (u16*)ws;                                  // 384 KB @ 0
    u16* qb = (u16*)(ws + (512 << 10));                   // 2 MB
    u16* kb = (u16*)(ws + (512 << 10) + (2 << 20));       // 2 MB
    u16* vT = (u16*)(ws + (512 << 10) + (4 << 20));       // 2 MB
    u16* Opb = (u16*)(ws + (8 << 20));                    // 8.4 MB
    float* Lp = (float*)(ws + (20 << 20));                // 256 KB

    wt_pack<<<1024, 192, 0, stream>>>(Wq, Wk, Wv, Wtt);
    qkv_gemm<<<768, 256, 0, stream>>>(x, Wtt, qb, kb, vT);
    attn_part<<<640, 256, 0, stream>>>(qb, kb, vT, Opb, Lp);
    attn_combine<<<512, 256, 0, stream>>>(Opb, Lp, out);
}

// Round 16
// 58.049 us; speedup vs baseline: 1.0408x; 1.0408x over previous
//
#include <hip/hip_runtime.h>

typedef unsigned short u16;
typedef __attribute__((ext_vector_type(4))) float f32x4;
typedef __attribute__((ext_vector_type(8))) short bf16x8;
typedef __attribute__((ext_vector_type(4))) u16 u16x4;
typedef __attribute__((ext_vector_type(8))) u16 u16x8;

#define MFMA(a, b, c) __builtin_amdgcn_mfma_f32_16x16x32_bf16(a, b, c, 0, 0, 0)

__device__ __forceinline__ u16 f2bf(float f) {
    unsigned u = __float_as_uint(f);
    u += 0x7fffu + ((u >> 16) & 1u);   // round-to-nearest-even
    return (u16)(u >> 16);
}
__device__ __forceinline__ float bf2f(u16 h) {
    unsigned u = ((unsigned)h) << 16;
    return __uint_as_float(u);
}

__device__ __forceinline__ void load_lds16(const void* g, void* l) {
    __builtin_amdgcn_global_load_lds((const __attribute__((address_space(1))) void*)g,
                                     (__attribute__((address_space(3))) void*)l,
                                     16, 0, 0);
}

// ---------------------------------------------------------------------------
// Kernel 1: pack Wq|Wk|Wv (fp32 [1024][64]) -> Wtt bf16 as 2 n-tiles of 96
// cols, per-(nt,kt) 12KB tiles, swizzled: Wtt[(nt*16+kt)*96 + nl][ ((c ^
// (nl&7))<<3)+ci ]. Tiles stage linearly into LDS.
// ---------------------------------------------------------------------------
__global__ void wt_pack(const float* __restrict__ Wq, const float* __restrict__ Wk,
                        const float* __restrict__ Wv, u16* __restrict__ Wtt) {
    const int k = blockIdx.x;        // 0..1023
    const int n = threadIdx.x;       // 0..191 (global col: 0-63 q, 64-127 k, 128-191 v)
    const float* W = (n < 64) ? Wq : (n < 128 ? Wk : Wv);
    const float v = W[(size_t)k * 64 + (n & 63)];
    const int nt = n / 96, nl = n % 96;
    const int kt = k >> 6, ks = k & 63, c = ks >> 3, ci = ks & 7;
    Wtt[(size_t)((nt * 16 + kt) * 96 + nl) * 64 + (((c ^ (nl & 7)) << 3) + ci)] = f2bf(v);
}

// ---------------------------------------------------------------------------
// Kernel 2: qkv projection, BM=64 x BN=96 (staged-bytes-optimal under
// grid>=512): x staged 128MB + Wt 96MB = 224MB total (vs 256MB at BM=32).
// Grid 512 (mt = bid>>1, nt = bid&1), 4 waves 2Mx2N (wave: 32 rows x 48 cols),
// LDS 56KB dbuf -> 2 blocks/CU. m97 2-phase staging, 64-wide swizzles.
// Q pre-scaled by log2(e)/sqrt(1024).
// ---------------------------------------------------------------------------
__global__ __launch_bounds__(256, 2) void qkv_gemm(const float* __restrict__ x,
                                                   const u16* __restrict__ Wtt,
                                                   u16* __restrict__ qo,
                                                   u16* __restrict__ ko,
                                                   u16* __restrict__ vT) {
    const int tid = threadIdx.x;
    const int lane = tid & 63, wave = tid >> 6;
    const int lr = lane & 15, lg = lane >> 4;
    const int wr = wave >> 1, wc = wave & 1;
    const int mt = blockIdx.x >> 1, nt = blockIdx.x & 1;
    const int m0 = mt * 64;

    __shared__ __align__(16) float xs[2][64 * 64];   // 16KB each
    __shared__ __align__(16) u16 ws[2][96 * 64];     // 12KB each

    f32x4 acc[2][3];
#pragma unroll
    for (int m = 0; m < 2; ++m)
#pragma unroll
        for (int n = 0; n < 3; ++n) acc[m][n] = (f32x4){0.f, 0.f, 0.f, 0.f};

#define QSTAGE(bufi, kt_)                                                               \
    {                                                                                   \
        _Pragma("unroll") for (int j = 0; j < 4; ++j) {                                 \
            const int cid = j * 256 + tid;                                              \
            const int row = cid >> 4, cc = cid & 15;                                    \
            load_lds16(x + (size_t)(m0 + row) * 1024 + (kt_)*64 +                       \
                           ((cc ^ (row & 7)) << 2),                                     \
                       &xs[bufi][(j * 256 + wave * 64) * 4]);                           \
        }                                                                               \
        _Pragma("unroll") for (int j = 0; j < 3; ++j) {                                 \
            const int cid = j * 256 + tid;                                              \
            load_lds16(Wtt + (size_t)((nt * 16 + (kt_)) * 96) * 64 + cid * 8,           \
                       &ws[bufi][(j * 256 + wave * 64) * 8]);                           \
        }                                                                               \
    }

    QSTAGE(0, 0);
    __syncthreads();

    for (int kt = 0; kt < 16; ++kt) {
        const int cur = kt & 1;
        if (kt < 15) QSTAGE(cur ^ 1, kt + 1);

#pragma unroll
        for (int h = 0; h < 2; ++h) {
            bf16x8 a[2];
#pragma unroll
            for (int mm = 0; mm < 2; ++mm) {
                const int rr = wr * 32 + mm * 16 + lr;
                const int c0 = h * 8 + lg * 2;
                f32x4 f0 = *(const f32x4*)&xs[cur][rr * 64 + ((c0 ^ (rr & 7)) << 2)];
                f32x4 f1 = *(const f32x4*)&xs[cur][rr * 64 + (((c0 + 1) ^ (rr & 7)) << 2)];
                bf16x8 t;
#pragma unroll
                for (int i = 0; i < 4; ++i) {
                    t[i] = (short)f2bf(f0[i]);
                    t[i + 4] = (short)f2bf(f1[i]);
                }
                a[mm] = t;
            }
#pragma unroll
            for (int nl = 0; nl < 3; ++nl) {
                const int row = wc * 48 + nl * 16 + lr;   // within-96 col index
                const int cb = h * 4 + lg;
                const bf16x8 b = *(const bf16x8*)&ws[cur][row * 64 + ((cb ^ (row & 7)) << 3)];
                acc[0][nl] = MFMA(a[0], b, acc[0][nl]);
                acc[1][nl] = MFMA(a[1], b, acc[1][nl]);
            }
        }
        __syncthreads();
    }

    const float SCQ = 0.0450842200277801f;   // log2(e)/sqrt(1024)
    const int bb = m0 >> 11;
    const int tb = m0 & 2047;
#pragma unroll
    for (int mm = 0; mm < 2; ++mm)
#pragma unroll
        for (int nl = 0; nl < 3; ++nl) {
            const int col = nt * 96 + wc * 48 + nl * 16 + lr;   // global col 0..191
            const int rl = wr * 32 + mm * 16 + lg * 4;
            if (col < 64) {
#pragma unroll
                for (int r = 0; r < 4; ++r)
                    qo[(size_t)(m0 + rl + r) * 64 + col] = f2bf(acc[mm][nl][r] * SCQ);
            } else if (col < 128) {
#pragma unroll
                for (int r = 0; r < 4; ++r)
                    ko[(size_t)(m0 + rl + r) * 64 + (col - 64)] = f2bf(acc[mm][nl][r]);
            } else {
                u16x4 pk;
#pragma unroll
                for (int r = 0; r < 4; ++r) pk[r] = f2bf(acc[mm][nl][r]);
                *(u16x4*)&vT[(size_t)(bb * 64 + (col - 128)) * 2048 + tb + rl] = pk;
            }
        }
}

// ---------------------------------------------------------------------------
// Kernel 3: causal attention — R13 structure + s_setprio (best known).
// ---------------------------------------------------------------------------
#define PPITCH 72
__global__ __launch_bounds__(256, 3) void attn_part(const u16* __restrict__ q,
                                                    const u16* __restrict__ k,
                                                    const u16* __restrict__ vT,
                                                    u16* __restrict__ Opb,
                                                    float* __restrict__ Lp) {
    const int b = blockIdx.x & 7;
    int g = blockIdx.x >> 3;                  // 0..79, heavy-first
    int qt = 31, rem = g;
    while (rem >= (qt >> 3) + 1) { rem -= (qt >> 3) + 1; --qt; }
    const int c0 = rem;
    const int q0 = qt * 64;
    const int kv_lo = c0 * 512;
    const int kv_hi = min(kv_lo + 512, q0 + 64);
    const int ntiles = (kv_hi - kv_lo) >> 6;
    const int slot = (b * 32 + qt) * 4 + c0;

    __shared__ __align__(16) u16 lK[2][64 * 64];     // 8KB each
    __shared__ __align__(16) u16 lV[2][64 * 64];     // 8KB each
    __shared__ __align__(16) u16 lP[4][16 * PPITCH]; // per-wave P

    const int tid = threadIdx.x;
    const int wave = tid >> 6, lane = tid & 63;
    const int lr = lane & 15, lg = lane >> 4;

    const u16* qb = q + (size_t)b * 2048 * 64;
    const u16* kb = k + (size_t)b * 2048 * 64;
    const u16* vb = vT + (size_t)b * 64 * 2048;

    const int myrow = q0 + wave * 16 + lr;
    const bf16x8 qf0 = *(const bf16x8*)(qb + (size_t)myrow * 64 + lg * 8);
    const bf16x8 qf1 = *(const bf16x8*)(qb + (size_t)myrow * 64 + 32 + lg * 8);

    f32x4 oacc[4];
#pragma unroll
    for (int n = 0; n < 4; ++n) oacc[n] = (f32x4){0.f, 0.f, 0.f, 0.f};
    float rs = 0.f;

#define ASTAGE(bufi, kv0_)                                                             \
    {                                                                                  \
        _Pragma("unroll") for (int j = 0; j < 2; ++j) {                                \
            const int cid = j * 256 + wave * 64 + lane;                                \
            const int row = cid >> 3, cc = cid & 7;                                    \
            load_lds16(kb + (size_t)((kv0_) + row) * 64 + ((cc ^ (row & 7)) << 3),     \
                       &lK[bufi][(j * 256 + wave * 64) * 8]);                          \
            load_lds16(vb + (size_t)row * 2048 + (kv0_) + ((cc ^ (row & 7)) << 3),     \
                       &lV[bufi][(j * 256 + wave * 64) * 8]);                          \
        }                                                                              \
    }

    ASTAGE(0, kv_lo);
    __syncthreads();

    for (int it = 0; it < ntiles; ++it) {
        const int cur = it & 1;
        if (it + 1 < ntiles) ASTAGE(cur ^ 1, kv_lo + (it + 1) * 64);

        const int kv0 = kv_lo + it * 64;
        if (kv0 <= q0 + wave * 16 + 15) {      // wave-uniform causal guard
            f32x4 s[4];
            __builtin_amdgcn_s_setprio(1);
#pragma unroll
            for (int n = 0; n < 4; ++n) {
                const int row = n * 16 + lr;
                const bf16x8 kf0 = *(const bf16x8*)&lK[cur][row * 64 + ((lg ^ (row & 7)) << 3)];
                const bf16x8 kf1 =
                    *(const bf16x8*)&lK[cur][row * 64 + (((4 + lg) ^ (row & 7)) << 3)];
                f32x4 a = (f32x4){0.f, 0.f, 0.f, 0.f};
                a = MFMA(kf0, qf0, a);
                a = MFMA(kf1, qf1, a);
                s[n] = a;   // S^T: rows kv = 16n+lg*4+r, col q = lr
            }
            __builtin_amdgcn_s_setprio(0);

            const bool msk = (kv0 + 63 > q0 + wave * 16);
#pragma unroll
            for (int n = 0; n < 4; ++n) {
                u16x4 pk;
#pragma unroll
                for (int r = 0; r < 4; ++r) {
                    const int kvi = kv0 + n * 16 + lg * 4 + r;
                    const float p = (!msk || kvi <= myrow) ? exp2f(s[n][r]) : 0.f;
                    rs += p;
                    pk[r] = f2bf(p);
                }
                *(u16x4*)&lP[wave][lr * PPITCH + n * 16 + lg * 4] = pk;
            }

            __builtin_amdgcn_s_setprio(1);
#pragma unroll
            for (int kc = 0; kc < 2; ++kc) {
                const bf16x8 pf = *(const bf16x8*)&lP[wave][lr * PPITCH + kc * 32 + lg * 8];
#pragma unroll
                for (int n = 0; n < 4; ++n) {
                    const int row = n * 16 + lr;
                    const bf16x8 vf =
                        *(const bf16x8*)&lV[cur][row * 64 + (((kc * 4 + lg) ^ (row & 7)) << 3)];
                    oacc[n] = MFMA(pf, vf, oacc[n]);
                }
            }
            __builtin_amdgcn_s_setprio(0);
        }
        __syncthreads();
    }

    // ---- row-sum across the 4 lanes sharing lr
    rs += __shfl_xor(rs, 16);
    rs += __shfl_xor(rs, 32);
    if (lane < 16) Lp[slot * 64 + wave * 16 + lr] = rs;

    // ---- bf16 partials, MFMA-native layout
    u16* op = Opb + (size_t)slot * 4096 + wave * 1024;
#pragma unroll
    for (int n = 0; n < 4; ++n)
#pragma unroll
        for (int r = 0; r < 4; ++r)
            op[n * 256 + (lg * 4 + r) * 16 + lr] = f2bf(oacc[n][r]);
}

// ---------------------------------------------------------------------------
// Kernel 4: vectorized merge (unchanged from R13).
// ---------------------------------------------------------------------------
__global__ __launch_bounds__(256) void attn_combine(const u16* __restrict__ Opb,
                                                    const float* __restrict__ Lp,
                                                    float* __restrict__ out) {
    const int gid = blockIdx.x * 256 + threadIdx.x;   // 131072
    const int colg = gid & 7;
    const int row = gid >> 3;            // b*2048 + t
    const int b = row >> 11, tt = row & 2047;
    const int qt = tt >> 6, i = tt & 63;
    const int nc = (qt >> 3) + 1;
    const size_t sbase = (size_t)(b * 32 + qt) * 4;
    const int sub0 = (i >> 4) * 1024 + (colg >> 1) * 256 + (i & 15) * 16 + (colg & 1) * 8;

    float O[8] = {0.f, 0.f, 0.f, 0.f, 0.f, 0.f, 0.f, 0.f};
    float L = 0.f;
    for (int c = 0; c < nc; ++c) {
        const u16x8 v = *(const u16x8*)&Opb[(sbase + c) * 4096 + sub0];
#pragma unroll
        for (int j = 0; j < 8; ++j) O[j] += bf2f(v[j]);
        L += Lp[(sbase + c) * 64 + i];
    }
    const float rinv = 1.0f / L;
    f32x4 o0, o1;
#pragma unroll
    for (int j = 0; j < 4; ++j) {
        o0[j] = O[j] * rinv;
        o1[j] = O[4 + j] * rinv;
    }
    float* ob = out + (size_t)row * 64 + colg * 8;
    *(f32x4*)(ob) = o0;
    *(f32x4*)(ob + 4) = o1;
}

// ---------------------------------------------------------------------------
extern "C" void kernel_launch(void* const* d_in, const int* in_sizes, int n_in,
                              void* d_out, int out_size, void* d_ws, size_t ws_size,
                              hipStream_t stream) {
    const float* x = (const float*)d_in[0];
    const float* Wq = (const float*)d_in[1];
    const float* Wk = (const float*)d_in[2];
    const float* Wv = (const float*)d_in[3];
    float* out = (float*)d_out;

    char* ws = (char*)d_ws;
    u16* Wtt = (u16*)ws;                                  // 384 KB @ 0
    u16* qb = (u16*)(ws + (512 << 10));                   // 2 MB
    u16* kb = (u16*)(ws + (512 << 10) + (2 << 20));       // 2 MB
    u16* vT = (u16*)(ws + (512 << 10) + (4 << 20));       // 2 MB
    u16* Opb = (u16*)(ws + (8 << 20));                    // 8.4 MB
    float* Lp = (float*)(ws + (20 << 20));                // 256 KB

    wt_pack<<<1024, 192, 0, stream>>>(Wq, Wk, Wv, Wtt);
    qkv_gemm<<<512, 256, 0, stream>>>(x, Wtt, qb, kb, vT);
    attn_part<<<640, 256, 0, stream>>>(qb, kb, vT, Opb, Lp);
    attn_combine<<<512, 256, 0, stream>>>(Opb, Lp, out);
}

// Round 17
// 55.016 us; speedup vs baseline: 1.0982x; 1.0551x over previous
//
#include <hip/hip_runtime.h>

typedef unsigned short u16;
typedef __attribute__((ext_vector_type(4))) float f32x4;
typedef __attribute__((ext_vector_type(8))) short bf16x8;
typedef __attribute__((ext_vector_type(4))) u16 u16x4;
typedef __attribute__((ext_vector_type(8))) u16 u16x8;

#define MFMA(a, b, c) __builtin_amdgcn_mfma_f32_16x16x32_bf16(a, b, c, 0, 0, 0)

__device__ __forceinline__ u16 f2bf(float f) {
    unsigned u = __float_as_uint(f);
    u += 0x7fffu + ((u >> 16) & 1u);   // round-to-nearest-even
    return (u16)(u >> 16);
}
__device__ __forceinline__ float bf2f(u16 h) {
    unsigned u = ((unsigned)h) << 16;
    return __uint_as_float(u);
}

__device__ __forceinline__ void load_lds16(const void* g, void* l) {
    __builtin_amdgcn_global_load_lds((const __attribute__((address_space(1))) void*)g,
                                     (__attribute__((address_space(3))) void*)l,
                                     16, 0, 0);
}

// ---------------------------------------------------------------------------
// Kernel 1: pack Wq|Wk|Wv (fp32 [1024][64]) -> Wtt bf16, tile-major + swizzled
// (R13 layout): Wtt[kt*12288 + n*64 + ((c^(n&7))<<3)+ci].
// ---------------------------------------------------------------------------
__global__ void wt_pack(const float* __restrict__ Wq, const float* __restrict__ Wk,
                        const float* __restrict__ Wv, u16* __restrict__ Wtt) {
    const int k = blockIdx.x;        // 0..1023
    const int n = threadIdx.x;       // 0..191
    const float* W = (n < 64) ? Wq : (n < 128 ? Wk : Wv);
    const float v = W[(size_t)k * 64 + (n & 63)];
    const int kt = k >> 6, ks = k & 63, c = ks >> 3, ci = ks & 7;
    Wtt[(size_t)kt * 12288 + n * 64 + (((c ^ (n & 7)) << 3) + ci)] = f2bf(v);
}

// ---------------------------------------------------------------------------
// Kernel 2: qkv projection — T3/T4 counted-vmcnt 3-deep pipeline.
// BM=64, N=192, BK=64, 512 thr (8 waves 2Mx4N), grid 256 = 1 block/CU (no
// tail). LDS 120KB triple-buffered. Per iter: vmcnt(5) keeps stage(t+1)'s
// 5 loads/thread in flight across the barrier (never drains to 0 until the
// tail). Staged bytes 160MB (vs R13's 256MB). Q pre-scaled by log2e/32.
// ---------------------------------------------------------------------------
__global__ __launch_bounds__(512, 2) void qkv_gemm(const float* __restrict__ x,
                                                   const u16* __restrict__ Wtt,
                                                   u16* __restrict__ qo,
                                                   u16* __restrict__ ko,
                                                   u16* __restrict__ vT) {
    const int tid = threadIdx.x;
    const int lane = tid & 63, wave = tid >> 6;
    const int lr = lane & 15, lg = lane >> 4;
    const int wr = wave >> 2, wc = wave & 3;      // 2M x 4N
    const int m0 = blockIdx.x * 64;

    __shared__ __align__(16) float xs[3][64 * 64];   // 16KB each
    __shared__ __align__(16) u16 ws[3][192 * 64];    // 24KB each

    f32x4 acc[2][3];
#pragma unroll
    for (int m = 0; m < 2; ++m)
#pragma unroll
        for (int n = 0; n < 3; ++n) acc[m][n] = (f32x4){0.f, 0.f, 0.f, 0.f};

    // 5 gload_lds per thread per stage: 2 xs (16KB) + 3 ws (24KB).
#define QSTAGE(bufi, kt_)                                                               \
    {                                                                                   \
        _Pragma("unroll") for (int j = 0; j < 2; ++j) {                                 \
            const int cid = j * 512 + tid;                                              \
            const int row = cid >> 4, cc = cid & 15;                                    \
            load_lds16(x + (size_t)(m0 + row) * 1024 + (kt_)*64 +                       \
                           ((cc ^ (row & 7)) << 2),                                     \
                       &xs[bufi][(j * 512 + wave * 64) * 4]);                           \
        }                                                                               \
        _Pragma("unroll") for (int j = 0; j < 3; ++j) {                                 \
            const int cid = j * 512 + tid;                                              \
            load_lds16(Wtt + (size_t)(kt_)*12288 + cid * 8,                             \
                       &ws[bufi][(j * 512 + wave * 64) * 8]);                           \
        }                                                                               \
    }

    // ---- prologue: stages 0 and 1 issued; nothing waited yet.
    QSTAGE(0, 0);
    QSTAGE(1, 1);

    for (int kt = 0; kt < 16; ++kt) {
        const int cur = kt % 3;
        // ---- counted wait: stage kt fully landed (oldest-first); stage kt+1's
        //      5 loads may stay in flight. Tail drains to 0.
        if (kt < 15) {
            asm volatile("s_waitcnt vmcnt(5)" ::: "memory");
        } else {
            asm volatile("s_waitcnt vmcnt(0)" ::: "memory");
        }
        __builtin_amdgcn_s_barrier();
        __builtin_amdgcn_sched_barrier(0);

        // ---- issue stage kt+2 into buf[(kt+2)%3] (its prior readers, compute
        //      (kt-1), all finished before the barrier above).
        if (kt + 2 < 16) QSTAGE((kt + 2) % 3, kt + 2);

        // ---- compute tile kt
#pragma unroll
        for (int h = 0; h < 2; ++h) {
            bf16x8 a[2];
#pragma unroll
            for (int mm = 0; mm < 2; ++mm) {
                const int rr = wr * 32 + mm * 16 + lr;
                const int c0 = h * 8 + lg * 2;
                f32x4 f0 = *(const f32x4*)&xs[cur][rr * 64 + ((c0 ^ (rr & 7)) << 2)];
                f32x4 f1 = *(const f32x4*)&xs[cur][rr * 64 + (((c0 + 1) ^ (rr & 7)) << 2)];
                bf16x8 t;
#pragma unroll
                for (int i = 0; i < 4; ++i) {
                    t[i] = (short)f2bf(f0[i]);
                    t[i + 4] = (short)f2bf(f1[i]);
                }
                a[mm] = t;
            }
#pragma unroll
            for (int nl = 0; nl < 3; ++nl) {
                const int row = wc * 48 + nl * 16 + lr;
                const int cb = h * 4 + lg;
                const bf16x8 b = *(const bf16x8*)&ws[cur][row * 64 + ((cb ^ (row & 7)) << 3)];
                acc[0][nl] = MFMA(a[0], b, acc[0][nl]);
                acc[1][nl] = MFMA(a[1], b, acc[1][nl]);
            }
        }
    }

    const float SCQ = 0.0450842200277801f;   // log2(e)/sqrt(1024)
    const int bb = m0 >> 11;
    const int tb = m0 & 2047;
#pragma unroll
    for (int mm = 0; mm < 2; ++mm)
#pragma unroll
        for (int nl = 0; nl < 3; ++nl) {
            const int col = wc * 48 + nl * 16 + lr;
            const int rl = wr * 32 + mm * 16 + lg * 4;
            if (col < 64) {
#pragma unroll
                for (int r = 0; r < 4; ++r)
                    qo[(size_t)(m0 + rl + r) * 64 + col] = f2bf(acc[mm][nl][r] * SCQ);
            } else if (col < 128) {
#pragma unroll
                for (int r = 0; r < 4; ++r)
                    ko[(size_t)(m0 + rl + r) * 64 + (col - 64)] = f2bf(acc[mm][nl][r]);
            } else {
                u16x4 pk;
#pragma unroll
                for (int r = 0; r < 4; ++r) pk[r] = f2bf(acc[mm][nl][r]);
                *(u16x4*)&vT[(size_t)(bb * 64 + (col - 128)) * 2048 + tb + rl] = pk;
            }
        }
}

// ---------------------------------------------------------------------------
// Kernel 3: causal attention — R13 structure + s_setprio (best known).
// ---------------------------------------------------------------------------
#define PPITCH 72
__global__ __launch_bounds__(256, 3) void attn_part(const u16* __restrict__ q,
                                                    const u16* __restrict__ k,
                                                    const u16* __restrict__ vT,
                                                    u16* __restrict__ Opb,
                                                    float* __restrict__ Lp) {
    const int b = blockIdx.x & 7;
    int g = blockIdx.x >> 3;                  // 0..79, heavy-first
    int qt = 31, rem = g;
    while (rem >= (qt >> 3) + 1) { rem -= (qt >> 3) + 1; --qt; }
    const int c0 = rem;
    const int q0 = qt * 64;
    const int kv_lo = c0 * 512;
    const int kv_hi = min(kv_lo + 512, q0 + 64);
    const int ntiles = (kv_hi - kv_lo) >> 6;
    const int slot = (b * 32 + qt) * 4 + c0;

    __shared__ __align__(16) u16 lK[2][64 * 64];     // 8KB each
    __shared__ __align__(16) u16 lV[2][64 * 64];     // 8KB each
    __shared__ __align__(16) u16 lP[4][16 * PPITCH]; // per-wave P

    const int tid = threadIdx.x;
    const int wave = tid >> 6, lane = tid & 63;
    const int lr = lane & 15, lg = lane >> 4;

    const u16* qb = q + (size_t)b * 2048 * 64;
    const u16* kb = k + (size_t)b * 2048 * 64;
    const u16* vb = vT + (size_t)b * 64 * 2048;

    const int myrow = q0 + wave * 16 + lr;
    const bf16x8 qf0 = *(const bf16x8*)(qb + (size_t)myrow * 64 + lg * 8);
    const bf16x8 qf1 = *(const bf16x8*)(qb + (size_t)myrow * 64 + 32 + lg * 8);

    f32x4 oacc[4];
#pragma unroll
    for (int n = 0; n < 4; ++n) oacc[n] = (f32x4){0.f, 0.f, 0.f, 0.f};
    float rs = 0.f;

#define ASTAGE(bufi, kv0_)                                                             \
    {                                                                                  \
        _Pragma("unroll") for (int j = 0; j < 2; ++j) {                                \
            const int cid = j * 256 + wave * 64 + lane;                                \
            const int row = cid >> 3, cc = cid & 7;                                    \
            load_lds16(kb + (size_t)((kv0_) + row) * 64 + ((cc ^ (row & 7)) << 3),     \
                       &lK[bufi][(j * 256 + wave * 64) * 8]);                          \
            load_lds16(vb + (size_t)row * 2048 + (kv0_) + ((cc ^ (row & 7)) << 3),     \
                       &lV[bufi][(j * 256 + wave * 64) * 8]);                          \
        }                                                                              \
    }

    ASTAGE(0, kv_lo);
    __syncthreads();

    for (int it = 0; it < ntiles; ++it) {
        const int cur = it & 1;
        if (it + 1 < ntiles) ASTAGE(cur ^ 1, kv_lo + (it + 1) * 64);

        const int kv0 = kv_lo + it * 64;
        if (kv0 <= q0 + wave * 16 + 15) {      // wave-uniform causal guard
            f32x4 s[4];
            __builtin_amdgcn_s_setprio(1);
#pragma unroll
            for (int n = 0; n < 4; ++n) {
                const int row = n * 16 + lr;
                const bf16x8 kf0 = *(const bf16x8*)&lK[cur][row * 64 + ((lg ^ (row & 7)) << 3)];
                const bf16x8 kf1 =
                    *(const bf16x8*)&lK[cur][row * 64 + (((4 + lg) ^ (row & 7)) << 3)];
                f32x4 a = (f32x4){0.f, 0.f, 0.f, 0.f};
                a = MFMA(kf0, qf0, a);
                a = MFMA(kf1, qf1, a);
                s[n] = a;   // S^T: rows kv = 16n+lg*4+r, col q = lr
            }
            __builtin_amdgcn_s_setprio(0);

            const bool msk = (kv0 + 63 > q0 + wave * 16);
#pragma unroll
            for (int n = 0; n < 4; ++n) {
                u16x4 pk;
#pragma unroll
                for (int r = 0; r < 4; ++r) {
                    const int kvi = kv0 + n * 16 + lg * 4 + r;
                    const float p = (!msk || kvi <= myrow) ? exp2f(s[n][r]) : 0.f;
                    rs += p;
                    pk[r] = f2bf(p);
                }
                *(u16x4*)&lP[wave][lr * PPITCH + n * 16 + lg * 4] = pk;
            }

            __builtin_amdgcn_s_setprio(1);
#pragma unroll
            for (int kc = 0; kc < 2; ++kc) {
                const bf16x8 pf = *(const bf16x8*)&lP[wave][lr * PPITCH + kc * 32 + lg * 8];
#pragma unroll
                for (int n = 0; n < 4; ++n) {
                    const int row = n * 16 + lr;
                    const bf16x8 vf =
                        *(const bf16x8*)&lV[cur][row * 64 + (((kc * 4 + lg) ^ (row & 7)) << 3)];
                    oacc[n] = MFMA(pf, vf, oacc[n]);
                }
            }
            __builtin_amdgcn_s_setprio(0);
        }
        __syncthreads();
    }

    // ---- row-sum across the 4 lanes sharing lr
    rs += __shfl_xor(rs, 16);
    rs += __shfl_xor(rs, 32);
    if (lane < 16) Lp[slot * 64 + wave * 16 + lr] = rs;

    // ---- bf16 partials, MFMA-native layout
    u16* op = Opb + (size_t)slot * 4096 + wave * 1024;
#pragma unroll
    for (int n = 0; n < 4; ++n)
#pragma unroll
        for (int r = 0; r < 4; ++r)
            op[n * 256 + (lg * 4 + r) * 16 + lr] = f2bf(oacc[n][r]);
}

// ---------------------------------------------------------------------------
// Kernel 4: vectorized merge (unchanged from R13).
// ---------------------------------------------------------------------------
__global__ __launch_bounds__(256) void attn_combine(const u16* __restrict__ Opb,
                                                    const float* __restrict__ Lp,
                                                    float* __restrict__ out) {
    const int gid = blockIdx.x * 256 + threadIdx.x;   // 131072
    const int colg = gid & 7;
    const int row = gid >> 3;            // b*2048 + t
    const int b = row >> 11, tt = row & 2047;
    const int qt = tt >> 6, i = tt & 63;
    const int nc = (qt >> 3) + 1;
    const size_t sbase = (size_t)(b * 32 + qt) * 4;
    const int sub0 = (i >> 4) * 1024 + (colg >> 1) * 256 + (i & 15) * 16 + (colg & 1) * 8;

    float O[8] = {0.f, 0.f, 0.f, 0.f, 0.f, 0.f, 0.f, 0.f};
    float L = 0.f;
    for (int c = 0; c < nc; ++c) {
        const u16x8 v = *(const u16x8*)&Opb[(sbase + c) * 4096 + sub0];
#pragma unroll
        for (int j = 0; j < 8; ++j) O[j] += bf2f(v[j]);
        L += Lp[(sbase + c) * 64 + i];
    }
    const float rinv = 1.0f / L;
    f32x4 o0, o1;
#pragma unroll
    for (int j = 0; j < 4; ++j) {
        o0[j] = O[j] * rinv;
        o1[j] = O[4 + j] * rinv;
    }
    float* ob = out + (size_t)row * 64 + colg * 8;
    *(f32x4*)(ob) = o0;
    *(f32x4*)(ob + 4) = o1;
}

// ---------------------------------------------------------------------------
extern "C" void kernel_launch(void* const* d_in, const int* in_sizes, int n_in,
                              void* d_out, int out_size, void* d_ws, size_t ws_size,
                              hipStream_t stream) {
    const float* x = (const float*)d_in[0];
    const float* Wq = (const float*)d_in[1];
    const float* Wk = (const float*)d_in[2];
    const float* Wv = (const float*)d_in[3];
    float* out = (float*)d_out;

    char* ws = (char*)d_ws;
    u16* Wtt = (u16*)ws;                                  // 384 KB @ 0
    u16* qb = (u16*)(ws + (512 << 10));                   // 2 MB
    u16* kb = (u16*)(ws + (512 << 10) + (2 << 20));       // 2 MB
    u16* vT = (u16*)(ws + (512 << 10) + (4 << 20));       // 2 MB
    u16* Opb = (u16*)(ws + (8 << 20));                    // 8.4 MB
    float* Lp = (float*)(ws + (20 << 20));                // 256 KB

    wt_pack<<<1024, 192, 0, stream>>>(Wq, Wk, Wv, Wtt);
    qkv_gemm<<<256, 512, 0, stream>>>(x, Wtt, qb, kb, vT);
    attn_part<<<640, 256, 0, stream>>>(qb, kb, vT, Opb, Lp);
    attn_combine<<<512, 256, 0, stream>>>(Opb, Lp, out);
}